// Round 11
// baseline (1288.683 us; speedup 1.0000x reference)
//
#include <hip/hip_runtime.h>

#define BATCH 64
#define ATOMS 64
#define CIN 3
#define KS 8
#define H 224
#define W 224
#define OH 56
#define OW 56
#define NLAT (BATCH*ATOMS*OH*OW)   // 12,845,056
#define IMGSZ (OH*OW*ATOMS)        // 200,704 elems per image (channel-last)
#define LAM 0.1f
#define ETA 0.1f

typedef __attribute__((ext_vector_type(8)))  __bf16    bf16x8;
typedef __attribute__((ext_vector_type(8)))  _Float16  f16x8;
typedef __attribute__((ext_vector_type(16))) float     floatx16;

union FragU { uint4 u; bf16x8 v; };
union FragH { uint4 u; f16x8 v; };
union HalfBits { _Float16 h; unsigned short s; };

__device__ __forceinline__ float softthr(float u) {
    float p = u - LAM;  p = p > 0.f ? p : 0.f;
    float q = -u - LAM; q = q > 0.f ? q : 0.f;
    return p - q;
}
__device__ __forceinline__ unsigned short f2bf(float f) {   // RNE
    union { float f; unsigned int u; } c; c.f = f;
    unsigned int r = c.u + 0x7fffu + ((c.u >> 16) & 1u);
    return (unsigned short)(r >> 16);
}
__device__ __forceinline__ float bf2f(unsigned short h) {
    union { unsigned int u; float f; } c; c.u = ((unsigned int)h) << 16;
    return c.f;
}
__device__ __forceinline__ unsigned short f2h(float f) {    // fp16 bits, RNE
    HalfBits hb; hb.h = (_Float16)f; return hb.s;
}
__device__ __forceinline__ float h2f(unsigned short s) {
    HalfBits hb; hb.s = s; return (float)hb.h;
}

// DT[((c*8+y)*8+x)*64 + m] = D[m,c,y,x]
__global__ void prep_dt_kernel(const float* __restrict__ D,
                               float* __restrict__ DT) {
    int idx = blockIdx.x * 256 + threadIdx.x;
    if (idx < CIN*KS*KS*ATOMS) {
        int m = idx & 63;
        int r = idx >> 6;
        int xk = r & 7, y = (r >> 3) & 7, c = r >> 6;
        DT[idx] = D[((m*CIN + c)*KS + y)*KS + xk];
    }
}

// 9 table-sets (inclusion-exclusion for boundary classes), 9 dpq each.
// tbl: 0=T0(all) 1=-dY1 2=-dY2 3=-dX1 4=-dX2 5=+dC11 6=+dC12 7=+dC21 8=+dC22
__global__ void prep_gram_kernel(const float* __restrict__ DT,
                                 float* __restrict__ G) {
    int blk = blockIdx.x;              // td*16 + nchunk
    int td = blk >> 4;
    int tbl = td / 9, dpq = td % 9;
    int dp = dpq / 3, dq = dpq % 3;
    int di = 1 - dp, dj = 1 - dq;
    int ylo = (0 > -4*di) ? 0 : -4*di;
    int yhi = (8 < 8-4*di) ? 8 : 8-4*di;
    int xlo = (0 > -4*dj) ? 0 : -4*dj;
    int xhi = (8 < 8-4*dj) ? 8 : 8-4*dj;
    if (tbl==1 || tbl==5 || tbl==6) { if (yhi > 2) yhi = 2; }
    if (tbl==2 || tbl==7 || tbl==8) { if (ylo < 6) ylo = 6; }
    if (tbl==3 || tbl==5 || tbl==7) { if (xhi > 2) xhi = 2; }
    if (tbl==4 || tbl==6 || tbl==8) { if (xlo < 6) xlo = 6; }
    float sign = (tbl >= 1 && tbl <= 4) ? -1.f : 1.f;
    int t = threadIdx.x;
    int m = t & 63;
    int n = (blk & 15)*4 + (t >> 6);
    float s = 0.f;
    for (int c = 0; c < CIN; ++c)
        for (int y = ylo; y < yhi; ++y)
            for (int x = xlo; x < xhi; ++x)
                s += DT[((c*8+y)*8+x)*64 + m] *
                     DT[((c*8+y+4*di)*8 + (x+4*dj))*64 + n];
    G[td*4096 + n*64 + m] = sign * s;
}

// Pack G into MFMA A-operand layout, split FP16 hi/lo.
__global__ void prep_packg_kernel(const float* __restrict__ G,
                                  unsigned short* __restrict__ GAh,
                                  unsigned short* __restrict__ GAl) {
    int g = blockIdx.x * 256 + threadIdx.x;      // 162*256 = 41472 groups
    int lane = g & 63;
    int r = g >> 6;
    int kstep = r & 3; r >>= 2;
    int mhalf = r & 1; int td = r >> 1;          // tbl*9+dpq
    int m = mhalf*32 + (lane & 31);
    int n = kstep*16 + (lane >> 5)*8;
    const float* src = G + td*4096 + n*64 + m;
#pragma unroll
    for (int j = 0; j < 8; ++j) {
        float v = src[j*64];
        unsigned short h = f2h(v);
        GAh[g*8 + j] = h;
        GAl[g*8 + j] = f2h(v - h2f(h));
    }
}

// Pack D into MFMA A-layout for conv_b: K=192, k = c*64+y*8+x. (bf16 split)
__global__ void prep_packd_kernel(const float* __restrict__ D,
                                  unsigned short* __restrict__ DAh,
                                  unsigned short* __restrict__ DAl) {
    int g = blockIdx.x * 256 + threadIdx.x;
    if (g >= 1536) return;
    int lane = g & 63;
    int r = g >> 6;
    int kstep = r % 12, mhalf = r / 12;
    int m = mhalf*32 + (lane & 31);
    int k0 = kstep*16 + (lane >> 5)*8;
#pragma unroll
    for (int j = 0; j < 8; ++j) {
        float v = D[m*192 + k0 + j];
        unsigned short h = f2bf(v);
        DAh[g*8 + j] = h;
        DAl[g*8 + j] = f2bf(v - bf2f(h));
    }
}

// b = conv2d(x, D, stride4, pad2); u = 0.1*b. Output CHANNEL-LAST [i][j][n].
__global__ __launch_bounds__(256) void conv_b_kernel(
        const float* __restrict__ x,
        const unsigned short* __restrict__ DAh,
        const unsigned short* __restrict__ DAl,
        float* __restrict__ b, float* __restrict__ u) {
    __shared__ __align__(16) unsigned short xth[CIN*36*36];
    __shared__ __align__(16) unsigned short xtl[CIN*36*36];
    __shared__ float ot[64*65];
    int blk = blockIdx.x;
    int img = blk / 49, tile = blk % 49;
    int i0 = (tile / 7) * 8, j0 = (tile % 7) * 8;
    int t = threadIdx.x;
    int r0 = 4*i0 - 2, c0 = 4*j0 - 2;
    for (int f = t; f < CIN*36*36; f += 256) {
        int cc = f / 1296, rem = f % 1296;
        int rr = rem / 36, qq = rem % 36;
        int Y = r0 + rr, X = c0 + qq;
        float v = 0.f;
        if (Y >= 0 && Y < H && X >= 0 && X < W)
            v = x[((img*CIN + cc)*H + Y)*W + X];
        unsigned short h = f2bf(v);
        xth[f] = h;
        xtl[f] = f2bf(v - bf2f(h));
    }
    __syncthreads();
    int lane = t & 63, wave = t >> 6;
    int mhalf = wave & 1, poshalf = wave >> 1;
    int pos = poshalf*32 + (lane & 31), pi = pos >> 3, pj = pos & 7;
    int khalf = lane >> 5;
    floatx16 acc;
#pragma unroll
    for (int i = 0; i < 16; ++i) acc[i] = 0.f;
    const uint4* Ah4 = (const uint4*)DAh;
    const uint4* Al4 = (const uint4*)DAl;
#pragma unroll 3
    for (int kstep = 0; kstep < 12; ++kstep) {
        int k0 = kstep*16 + khalf*8;
        int cc = k0 >> 6, yy = (k0 >> 3) & 7;
        int boff = cc*1296 + (4*pi + yy)*36 + 4*pj;
        FragU ah, al, bh, bl;
        ah.u = Ah4[(mhalf*12 + kstep)*64 + lane];
        al.u = Al4[(mhalf*12 + kstep)*64 + lane];
        const uint2* ph = (const uint2*)(xth + boff);
        uint2 h0 = ph[0], h1 = ph[1];
        bh.u = make_uint4(h0.x, h0.y, h1.x, h1.y);
        const uint2* pl = (const uint2*)(xtl + boff);
        uint2 l0 = pl[0], l1 = pl[1];
        bl.u = make_uint4(l0.x, l0.y, l1.x, l1.y);
        acc = __builtin_amdgcn_mfma_f32_32x32x16_bf16(ah.v, bh.v, acc, 0, 0, 0);
        acc = __builtin_amdgcn_mfma_f32_32x32x16_bf16(ah.v, bl.v, acc, 0, 0, 0);
        acc = __builtin_amdgcn_mfma_f32_32x32x16_bf16(al.v, bh.v, acc, 0, 0, 0);
    }
#pragma unroll
    for (int r16 = 0; r16 < 16; ++r16) {
        int row = (r16 & 3) + 8*(r16 >> 2) + 4*khalf;
        ot[(mhalf*32 + row)*65 + pos] = acc[r16];
    }
    __syncthreads();
    // channel-last epilogue: lane = channel -> 256B contiguous stores
    int m = t & 63;
    float* bp = b + (size_t)img*IMGSZ;
    float* up = u + (size_t)img*IMGSZ;
#pragma unroll
    for (int e = 0; e < 16; ++e) {
        int pp = e*4 + (t >> 6);
        int gi = ((i0 + (pp >> 3))*OW + j0 + (pp & 7))*64 + m;
        float v = ot[m*65 + pp];
        bp[gi] = v;
        up[gi] = ETA * v;
    }
}

// One LCA step on a 2-row x 56-col band (channel-last state), FP16 GEMM.
// Concurrency tune: ot overlay shrunk to 120 rows (invalid pj>=56 lanes
// redirected to 8 scratch rows) -> LDS 31200 B -> 5 blocks/CU under
// __launch_bounds__(256,5) (VGPR cap 102; ~80 live -> no spill cliff).
// Epilogue unroll 7 -> 14 global loads in flight (the kernel is memory-
// latency-bound: R7/R8 showed achieved BW scales with outstanding reqs).
__global__ __launch_bounds__(256, 5) void lca_iter_kernel(
        const float* __restrict__ b, const float* __restrict__ uin,
        float* __restrict__ uout,
        const unsigned short* __restrict__ GAh,
        const unsigned short* __restrict__ GAl,
        float* __restrict__ out, int last) {
    __shared__ __align__(16) unsigned char smem[31200];   // max(29696, 31200)
    unsigned short* at2h = (unsigned short*)smem;         // [rc][swizzled n]
    int blk = blockIdx.x;
    int img = blk / 28, bandi = blk % 28;
    int i0 = bandi*2;
    int t = threadIdx.x;
    const float* ub = uin + (size_t)img*IMGSZ;
    // Phase 1: halo band (4 rows x 58 cols x 64 n) -> soft -> fp16 -> LDS.
    for (int idx = t; idx < 232*16; idx += 256) {
        int chunk = idx >> 4, f4 = idx & 15;
        int p = chunk / 58, q = chunk - 58*p;
        int gi = i0 - 1 + p, gj = q - 1;
        int n0 = f4 << 2;
        float4 v = make_float4(0.f, 0.f, 0.f, 0.f);
        if (gi >= 0 && gi < OH && gj >= 0 && gj < OW)
            v = *(const float4*)(ub + ((gi*OW + gj)*64 + n0));
        ushort4 hv = make_ushort4(f2h(softthr(v.x)), f2h(softthr(v.y)),
                                  f2h(softthr(v.z)), f2h(softthr(v.w)));
        int kg = n0 >> 3;
        int base = chunk*64 + ((kg ^ (chunk & 7)) << 3) + (n0 & 7);
        *(ushort4*)(at2h + base) = hv;
    }
    __syncthreads();
    int lane = t & 63, wave = t >> 6;
    int mhalf = wave & 1, cgrp = wave >> 1;      // cgrp: pj 0..31 / 32..63
    int khalf = lane >> 5, cl = lane & 31;
    int pj = cgrp*32 + cl;
    int pjx = (pj < 56) ? pj : 0;                // clamp invalid columns
    floatx16 acc0, acc1;
#pragma unroll
    for (int i = 0; i < 16; ++i) { acc0[i] = 0.f; acc1[i] = 0.f; }
    const uint4* Gh4 = (const uint4*)GAh;
    const uint4* Gl4 = (const uint4*)GAl;
    const uint4* B4h = (const uint4*)at2h;
    int tbx = (cgrp == 0) ? 3 : 4;               // X boundary table
    unsigned msel = (cl == ((cgrp == 0) ? 0 : 23)) ? 0xFFFFFFFFu : 0u;
    bool edge = (bandi == 0) || (bandi == 27);
    if (!edge) {
        // ---- interior fast path ----
#pragma unroll 1
        for (int dq = 0; dq < 3; ++dq) {
#pragma unroll 1
            for (int kstep = 0; kstep < 4; ++kstep) {
                int kg2 = kstep*2 + khalf;
                FragH B[4];
#pragma unroll
                for (int p = 0; p < 4; ++p) {
                    int rc = p*58 + pjx + dq;
                    B[p].u = B4h[rc*8 + (kg2 ^ (rc & 7))];
                }
#pragma unroll
                for (int dp = 0; dp < 3; ++dp) {
                    int abase = (((3*dp + dq)*2 + mhalf)*4 + kstep)*64 + lane;
                    FragH a0, a1, ax, bm0, bm1;
                    a0.u = Gh4[abase];
                    a1.u = Gl4[abase];
                    ax.u = Gh4[(tbx*9)*512 + abase];
                    bm0.u = make_uint4(B[dp].u.x & msel, B[dp].u.y & msel,
                                       B[dp].u.z & msel, B[dp].u.w & msel);
                    bm1.u = make_uint4(B[dp+1].u.x & msel, B[dp+1].u.y & msel,
                                       B[dp+1].u.z & msel, B[dp+1].u.w & msel);
                    acc0 = __builtin_amdgcn_mfma_f32_32x32x16_f16(a0.v, B[dp].v, acc0, 0,0,0);
                    acc1 = __builtin_amdgcn_mfma_f32_32x32x16_f16(a0.v, B[dp+1].v, acc1, 0,0,0);
                    acc0 = __builtin_amdgcn_mfma_f32_32x32x16_f16(a1.v, B[dp].v, acc0, 0,0,0);
                    acc1 = __builtin_amdgcn_mfma_f32_32x32x16_f16(a1.v, B[dp+1].v, acc1, 0,0,0);
                    acc0 = __builtin_amdgcn_mfma_f32_32x32x16_f16(ax.v, bm0.v, acc0, 0,0,0);
                    acc1 = __builtin_amdgcn_mfma_f32_32x32x16_f16(ax.v, bm1.v, acc1, 0,0,0);
                }
            }
        }
    } else {
        // ---- edge path (bandi 0 or 27): runtime term loop, nt = 6 ----
        int ymask, tby, tbc;
        if (bandi == 0) { ymask = 1; tby = 1; tbc = (cgrp == 0) ? 5 : 6; }
        else            { ymask = 2; tby = 2; tbc = (cgrp == 0) ? 7 : 8; }
#pragma unroll 1
        for (int dq = 0; dq < 3; ++dq) {
#pragma unroll 1
            for (int kstep = 0; kstep < 4; ++kstep) {
                int kg2 = kstep*2 + khalf;
#pragma unroll
                for (int dp = 0; dp < 3; ++dp) {
                    int rc0 = dp*58 + pjx + dq;
                    int rc1 = rc0 + 58;
                    FragH B0, B1;
                    B0.u = B4h[rc0*8 + (kg2 ^ (rc0 & 7))];
                    B1.u = B4h[rc1*8 + (kg2 ^ (rc1 & 7))];
                    for (int tm = 0; tm < 6; ++tm) {
                        int td = (tm < 2) ? 0 : (tm == 2) ? tbx : (tm < 5) ? tby : tbc;
                        const uint4* Ap = ((tm == 1) || (tm == 4)) ? Gl4 : Gh4;
                        bool masked = (tm == 2) || (tm == 5);
                        int am = (tm < 3) ? 3 : ymask;
                        FragH a;
                        a.u = Ap[(((td*9 + 3*dp + dq)*2 + mhalf)*4 + kstep)*64 + lane];
                        if (!masked) {
                            if (am & 1)
                                acc0 = __builtin_amdgcn_mfma_f32_32x32x16_f16(a.v, B0.v, acc0, 0,0,0);
                            if (am & 2)
                                acc1 = __builtin_amdgcn_mfma_f32_32x32x16_f16(a.v, B1.v, acc1, 0,0,0);
                        } else {
                            if (am & 1) {
                                FragH bm;
                                bm.u = make_uint4(B0.u.x & msel, B0.u.y & msel,
                                                  B0.u.z & msel, B0.u.w & msel);
                                acc0 = __builtin_amdgcn_mfma_f32_32x32x16_f16(a.v, bm.v, acc0, 0,0,0);
                            }
                            if (am & 2) {
                                FragH bm;
                                bm.u = make_uint4(B1.u.x & msel, B1.u.y & msel,
                                                  B1.u.z & msel, B1.u.w & msel);
                                acc1 = __builtin_amdgcn_mfma_f32_32x32x16_f16(a.v, bm.v, acc1, 0,0,0);
                            }
                        }
                    }
                }
            }
        }
    }
    __syncthreads();                   // at2 dead; overlay fp32 ot[site][m]
    float* ot = (float*)smem;          // 120*65*4 = 31200 B
    {
        int s0 = (pj < 56) ? pj        : (112 + (cl & 3));   // scratch rows
        int s1 = (pj < 56) ? (56 + pj) : (116 + (cl & 3));
#pragma unroll
        for (int r16 = 0; r16 < 16; ++r16) {
            int row = (r16 & 3) + 8*(r16 >> 2) + 4*khalf;
            int m = mhalf*32 + row;
            ot[s0*65 + m] = acc0[r16];
            ot[s1*65 + m] = acc1[r16];
        }
    }
    __syncthreads();
    const float* bp = b + (size_t)img*IMGSZ;
    float* up = uout + (size_t)img*IMGSZ;
#pragma unroll 7
    for (int pass = 0; pass < 28; ++pass) {     // 2*56*64 elems, lane = n
        int idx = pass*256 + t;
        int n = idx & 63;
        int rest = idx >> 6;                    // site 0..111
        int pi = (rest >= 56) ? 1 : 0;
        int j = rest - 56*pi;
        int g = ((i0 + pi)*OW + j)*64 + n;
        float uo = ub[g];
        float gram = ot[rest*65 + n];
        float un = uo + ETA * (bp[g] - uo - gram + softthr(uo));
        if (last) out[(((size_t)img*ATOMS + n)*OH + (i0 + pi))*OW + j] = softthr(un);
        else      up[g] = un;
    }
}

extern "C" void kernel_launch(void* const* d_in, const int* in_sizes, int n_in,
                              void* d_out, int out_size, void* d_ws, size_t ws_size,
                              hipStream_t stream) {
    const float* x = (const float*)d_in[0];
    const float* D = (const float*)d_in[1];
    float* out = (float*)d_out;
    float* ws = (float*)d_ws;
    float* b  = ws;                        // NLAT f32 (channel-last)
    float* u0 = b  + NLAT;                 // NLAT f32
    float* u1 = u0 + NLAT;                 // NLAT f32
    float* DT = u1 + NLAT;                 // 12288 f32
    float* Gf = DT + 12288;                // 81*4096 f32
    unsigned short* GAh = (unsigned short*)(Gf + 331776);
    unsigned short* GAl = GAh + 331776;
    unsigned short* DAh = GAl + 331776;
    unsigned short* DAl = DAh + 12288;
    prep_dt_kernel<<<48, 256, 0, stream>>>(D, DT);
    prep_gram_kernel<<<1296, 256, 0, stream>>>(DT, Gf);
    prep_packg_kernel<<<162, 256, 0, stream>>>(Gf, GAh, GAl);
    prep_packd_kernel<<<6, 256, 0, stream>>>(D, DAh, DAl);
    conv_b_kernel<<<BATCH*49, 256, 0, stream>>>(x, DAh, DAl, b, u0);
    float* uin = u0; float* uo2 = u1;
    for (int it = 0; it < 9; ++it) {       // iterations 2..10 (iter 1 folded)
        int last = (it == 8);
        lca_iter_kernel<<<BATCH*28, 256, 0, stream>>>(b, uin, uo2, GAh, GAl, out, last);
        float* tmp = uin; uin = uo2; uo2 = tmp;
    }
}